// Round 16
// baseline (377.210 us; speedup 1.0000x reference)
//
#include <hip/hip_runtime.h>

#define N_NODES 100000
#define N_EDGES 3200000
#define N_GRAPHS 2048
#define SSH 8                       // 256 dst nodes per superbucket
#define SSZ 256
#define NSB 391                     // ceil(100000/256)
#define FILL_BLOCKS 512
#define CHUNK 6250                  // N_EDGES / FILL_BLOCKS
#define NSL 49                      // src slices of 2048 nodes (49*2048 = 100352)
#define NBIN (SSZ * NSL)            // 12544 bins (50KB LDS)
#define DBLK 4096                   // dst nodes per agg block (8/thread, in registers)
#define NDB 25                      // ceil(100000/4096)
#define SPLIT 8
#define NPAD (NDB * DBLK)           // 102400
#define NROWS (NSL * 2048)          // 100352 padded table rows

typedef float f32x4 __attribute__((ext_vector_type(4)));

__device__ __forceinline__ void gAtomAdd(float* p, float v) { unsafeAtomicAdd(p, v); }

// slice -> position so split p's slices (t ≡ p mod 8) are contiguous ascending
__device__ __forceinline__ int slice_pidx(int t) {
  int p = t & 7;
  return (p ? 6 * p + 1 : 0) + (t >> 3);   // split sizes: 7,6,6,6,6,6,6,6
}

// ---------- pass 1: per-block superbucket histogram + reservation (proven) ----------
__global__ void kA_count(const int* __restrict__ dst, int* __restrict__ bcnt,
                         int* __restrict__ blockBase) {
  __shared__ int hist[NSB];
  int tid = threadIdx.x, blk = blockIdx.x;
  for (int i = tid; i < NSB; i += 256) hist[i] = 0;
  __syncthreads();
  int beg = blk * CHUNK, end = beg + CHUNK;
  for (int e = beg + tid; e < end; e += 256) atomicAdd(&hist[dst[e] >> SSH], 1);
  __syncthreads();
  for (int i = tid; i < NSB; i += 256) {
    int h = hist[i];
    if (h) blockBase[blk * NSB + i] = atomicAdd(&bcnt[i], h);
  }
}

// ---------- exclusive scan over NSB counts (proven) ----------
__global__ void k_bscan(const int* __restrict__ bcnt, int* __restrict__ sboffs) {
  __shared__ int sh[512];
  int tid = threadIdx.x;
  int v = (tid < NSB) ? bcnt[tid] : 0;
  sh[tid] = v;
  __syncthreads();
  for (int off = 1; off < 512; off <<= 1) {
    int t = (tid >= off) ? sh[tid - off] : 0;
    __syncthreads();
    sh[tid] += t;
    __syncthreads();
  }
  if (tid < NSB) sboffs[tid] = sh[tid] - v;
  if (tid == 0) sboffs[NSB] = N_EDGES;
}

// ---------- pass 2: scatter packed edges into superbucket segments (proven) ----------
__global__ void kB_fill(const int* __restrict__ src, const int* __restrict__ dst,
                        const int* __restrict__ sboffs, const int* __restrict__ blockBase,
                        unsigned* __restrict__ stage) {
  __shared__ int lbase[NSB];
  int tid = threadIdx.x, blk = blockIdx.x;
  for (int i = tid; i < NSB; i += 256) lbase[i] = sboffs[i] + blockBase[blk * NSB + i];
  __syncthreads();
  int beg = blk * CHUNK, end = beg + CHUNK;
  for (int e = beg + tid; e < end; e += 256) {
    int d = dst[e], s = src[e];
    int pos = atomicAdd(&lbase[d >> SSH], 1);
    stage[pos] = ((unsigned)s << SSH) | (unsigned)(d & (SSZ - 1));  // src:17 | dstloc:8
  }
}

// ---------- pass 3: per-superbucket (node, split-ordered slice) counting sort (proven r14) ----------
__global__ void kC_csr(const unsigned* __restrict__ stage, const int* __restrict__ sboffs,
                       const float* __restrict__ x, int* __restrict__ noffs,
                       int* __restrict__ noffsS, float* __restrict__ dinv,
                       float* __restrict__ xd5, int* __restrict__ csr) {
  __shared__ int bins[NBIN];                       // 50KB
  __shared__ int sc[SSZ];
  int b = blockIdx.x, tid = threadIdx.x;
  for (int i = tid; i < NBIN; i += 256) bins[i] = 0;
  __syncthreads();
  int beg = sboffs[b], end = sboffs[b + 1];
  for (int k = beg + tid; k < end; k += 256) {
    unsigned u = stage[k];
    int dl = u & (SSZ - 1), s = u >> SSH;
    atomicAdd(&bins[dl * NSL + slice_pidx(s >> 11)], 1);
  }
  __syncthreads();
  int tot = 0;
  for (int j = 0; j < NSL; j++) tot += bins[tid * NSL + j];
  sc[tid] = tot;
  __syncthreads();
  for (int off = 1; off < SSZ; off <<= 1) {
    int t = (tid >= off) ? sc[tid - off] : 0;
    __syncthreads();
    sc[tid] += t;
    __syncthreads();
  }
  int excl = sc[tid] - tot;
  int node = b * SSZ + tid;
  if (node <= N_NODES) noffs[node] = beg + excl;
  if (node < N_NODES) {
    float di = rsqrtf((float)(tot + 1));           // +1 self-loop
    dinv[node] = di;
#pragma unroll
    for (int c = 0; c < 5; c++) xd5[(size_t)node * 5 + c] = x[node * 5 + c] * di;
  }
  int run = beg + excl;
  for (int j = 0; j < NSL; j++) {
    int p = (j == 0) ? 0 : ((j >= 7 && (j - 7) % 6 == 0) ? 1 + (j - 7) / 6 : -1);
    if (p >= 0 && node < N_NODES) noffsS[node * 8 + p] = run;
    int c = bins[tid * NSL + j];
    bins[tid * NSL + j] = run;
    run += c;
  }
  __syncthreads();
  for (int k = beg + tid; k < end; k += 256) {
    unsigned u = stage[k];
    int dl = u & (SSZ - 1), s = u >> SSH;
    int pos = atomicAdd(&bins[dl * NSL + slice_pidx(s >> 11)], 1);
    csr[pos] = s;
  }
}

// ---------- tiled agg: reg double-buffered slice stream + register accumulation ----------
// NC=5: tab = xd5 packed 5 f/row, LDS stride 5. NC=8: tab = g2 8 f/row, LDS stride 9.
template <int NC>
__global__ void k_aggs(const int* __restrict__ csr, const int* __restrict__ noffs,
                       const int* __restrict__ noffsS, const float* __restrict__ tab,
                       float* __restrict__ partial) {
  constexpr int NCS = (NC == 5) ? 5 : 9;
  constexpr int NREG = (NC == 5) ? 5 : 8;          // float4s staged per thread
  constexpr int PS = (NC == 5) ? 5 : 8;            // partial row stride
  extern __shared__ float slice[];                 // 2048 * NCS floats
  int bx = blockIdx.x;
  int db = bx >> 3, p = bx & 7;
  int base = db * DBLK;
  int tid = threadIdx.x;                           // 512 threads, 8 nodes each
  const float4* tv = (const float4*)tab;

  int kcur[8], kend[8];
  float acc[8][NC];
#pragma unroll
  for (int i = 0; i < 8; i++) {
    int n = base + i * 512 + tid;
    if (n < N_NODES) {
      kcur[i] = noffsS[n * 8 + p];
      kend[i] = (p < 7) ? noffsS[n * 8 + p + 1] : noffs[n + 1];
    } else { kcur[i] = 0; kend[i] = 0; }
#pragma unroll
    for (int c = 0; c < NC; c++) acc[i][c] = 0.f;
  }

  float4 st[NREG];
  int nsl = (NSL - p + 7) / 8;
  {                                                // prologue: issue slice t=p
    size_t fb = (size_t)p * 2048 * NC / 4;
#pragma unroll
    for (int j = 0; j < NREG; j++) st[j] = tv[fb + tid + j * 512];
  }
  for (int si = 0; si < nsl; si++) {
    int t = p + si * 8;
    __syncthreads();                               // prior slice readers done
    if (NC == 5) {
#pragma unroll
      for (int j = 0; j < NREG; j++)               // pure linear copy, b128 LDS writes
        ((float4*)slice)[tid + j * 512] = st[j];
    } else {
#pragma unroll
      for (int j = 0; j < NREG; j++) {             // strided: row r at slice+r*9
        int q = tid + j * 512;
        float* dp = slice + (q >> 1) * 9 + (q & 1) * 4;
        dp[0] = st[j].x; dp[1] = st[j].y; dp[2] = st[j].z; dp[3] = st[j].w;
      }
    }
    __syncthreads();                               // slice visible
    if (si + 1 < nsl) {                            // issue next slice (overlaps processing)
      size_t fb = (size_t)(t + 8) * 2048 * NC / 4;
#pragma unroll
      for (int j = 0; j < NREG; j++) st[j] = tv[fb + tid + j * 512];
    }
#pragma unroll
    for (int i = 0; i < 8; i++) {
      int k = kcur[i], ke = kend[i];
      while (k < ke) {                             // contiguous sub-run, slice-ascending
        int s = csr[k];
        if ((s >> 11) != t) break;
        const float* sp = slice + (s & 2047) * NCS;
#pragma unroll
        for (int c = 0; c < NC; c++) acc[i][c] += sp[c];
        k++;
      }
      kcur[i] = k;
    }
  }
#pragma unroll
  for (int i = 0; i < 8; i++) {
    int n = base + i * 512 + tid;
    float* pp = partial + ((size_t)p * NPAD + n) * PS;
    if (NC == 8) {                                 // 32B-aligned rows: vector NT stores
      f32x4 v0 = {acc[i][0], acc[i][1], acc[i][2], acc[i][3]};
      f32x4 v1 = {acc[i][4], acc[i][5], acc[i][6], acc[i][7]};
      __builtin_nontemporal_store(v0, (f32x4*)pp);
      __builtin_nontemporal_store(v1, (f32x4*)(pp + 4));
    } else {                                       // 20B rows: scalar NT stores
#pragma unroll
      for (int c = 0; c < NC; c++) __builtin_nontemporal_store(acc[i][c], pp + c);
    }
  }
}

// ---------- layer-1 epilogue: merge partials + self-loop, fused MLP ----------
__global__ void k_mlp(const float* __restrict__ partial, const float* __restrict__ xd5,
                      const float* __restrict__ dinv, const float* __restrict__ W1,
                      const float* __restrict__ b1, const float* __restrict__ W2,
                      float* __restrict__ g2) {
  __shared__ float w1[150], bb1[30], w2[240];
  int tid = threadIdx.x;
  for (int i = tid; i < 150; i += 256) w1[i] = W1[i];
  for (int i = tid; i < 30; i += 256) bb1[i] = b1[i];
  for (int i = tid; i < 240; i += 256) w2[i] = W2[i];
  __syncthreads();
  int n = blockIdx.x * 256 + tid;
  if (n >= N_NODES) return;
  float di = dinv[n];
  float s[5];
#pragma unroll
  for (int c = 0; c < 5; c++) s[c] = xd5[(size_t)n * 5 + c];
#pragma unroll
  for (int p = 0; p < SPLIT; p++) {
    const float* pp = partial + ((size_t)p * NPAD + n) * 5;
#pragma unroll
    for (int c = 0; c < 5; c++) s[c] += pp[c];
  }
  float t[5] = {s[0] * di, s[1] * di, s[2] * di, s[3] * di, s[4] * di};
  float h[30];
#pragma unroll
  for (int j = 0; j < 30; j++) h[j] = bb1[j];
#pragma unroll
  for (int k = 0; k < 5; k++)
#pragma unroll
    for (int j = 0; j < 30; j++) h[j] += t[k] * w1[k * 30 + j];
  float g[8] = {0, 0, 0, 0, 0, 0, 0, 0};
#pragma unroll
  for (int j = 0; j < 30; j++) {
    float hj = fmaxf(h[j], 0.f);
#pragma unroll
    for (int c = 0; c < 8; c++) g[c] += hj * w2[j * 8 + c];
  }
  float4* gv = (float4*)g2;
  gv[n * 2]     = make_float4(g[0] * di, g[1] * di, g[2] * di, g[3] * di);
  gv[n * 2 + 1] = make_float4(g[4] * di, g[5] * di, g[6] * di, g[7] * di);
}

// ---------- layer-2 epilogue: merge partials + bias + pooling (proven r11/r14) ----------
__global__ void k_out(const float* __restrict__ partial, const float* __restrict__ g2,
                      const float* __restrict__ dinv, const float* __restrict__ b2,
                      const int* __restrict__ batch, float* __restrict__ gsum) {
  __shared__ float gpool[64 * 8];
  __shared__ float bb2[8];
  __shared__ int batch0s;
  int blk = blockIdx.x, tid = threadIdx.x;         // 512 threads
  for (int i = tid; i < 64 * 8; i += 512) gpool[i] = 0.f;
  if (tid < 8) bb2[tid] = b2[tid];
  if (tid == 0) {
    int n0 = blk * 512;
    batch0s = batch[n0 < N_NODES ? n0 : (N_NODES - 1)];
  }
  __syncthreads();
  int n = blk * 512 + tid;
  int batch0 = batch0s;
  if (n < N_NODES) {
    float di = dinv[n];
    int gid = batch[n], goff = gid - batch0;
    float4 s03 = ((const float4*)g2)[n * 2];
    float4 s47 = ((const float4*)g2)[n * 2 + 1];
#pragma unroll
    for (int p = 0; p < SPLIT; p++) {
      const float4* pp = (const float4*)(partial + ((size_t)p * NPAD + n) * 8);
      float4 qa = pp[0], qb = pp[1];
      s03.x += qa.x; s03.y += qa.y; s03.z += qa.z; s03.w += qa.w;
      s47.x += qb.x; s47.y += qb.y; s47.z += qb.z; s47.w += qb.w;
    }
    float val[8] = {di * s03.x + bb2[0], di * s03.y + bb2[1], di * s03.z + bb2[2],
                    di * s03.w + bb2[3], di * s47.x + bb2[4], di * s47.y + bb2[5],
                    di * s47.z + bb2[6], di * s47.w + bb2[7]};
#pragma unroll
    for (int c = 0; c < 8; c++) {
      if (goff < 64) atomicAdd(&gpool[goff * 8 + c], val[c]);
      else           gAtomAdd(&gsum[gid * 8 + c], val[c]);
    }
  }
  __syncthreads();
  for (int i = tid; i < 64 * 8; i += 512) {
    int gid = batch0 + (i >> 3);
    float v = gpool[i];
    if (gid < N_GRAPHS && v != 0.f) gAtomAdd(&gsum[gid * 8 + (i & 7)], v);
  }
}

// ---------- mean divide (proven) ----------
__global__ void k_final(const float* __restrict__ gsum, const int* __restrict__ batch,
                        float* __restrict__ out) {
  int i = blockIdx.x * 256 + threadIdx.x;
  if (i >= N_GRAPHS * 8) return;
  int g = i >> 3;
  int lo = 0, hi = N_NODES;
  while (lo < hi) { int m = (lo + hi) >> 1; if (batch[m] < g) lo = m + 1; else hi = m; }
  int lo2 = lo, hi2 = N_NODES;
  while (lo2 < hi2) { int m = (lo2 + hi2) >> 1; if (batch[m] <= g) lo2 = m + 1; else hi2 = m; }
  float c = (float)(lo2 - lo);
  out[i] = gsum[i] / fmaxf(c, 1.f);
}

extern "C" void kernel_launch(void* const* d_in, const int* in_sizes, int n_in,
                              void* d_out, int out_size, void* d_ws, size_t ws_size,
                              hipStream_t stream) {
  const float* x    = (const float*)d_in[0];
  const int* ei     = (const int*)d_in[1];
  const int* batch  = (const int*)d_in[2];
  const float* W1   = (const float*)d_in[3];
  const float* b1   = (const float*)d_in[4];
  const float* W2   = (const float*)d_in[5];
  const float* b2   = (const float*)d_in[6];
  const int* srcp = ei;
  const int* dstp = ei + N_EDGES;
  float* out = (float*)d_out;

  // workspace carve (~48 MB; partial overlays blockBase+stage which die after kC)
  char* base = (char*)d_ws;
  size_t o = 0;
  auto carve = [&](size_t bytes) -> char* {
    char* p = base + o;
    o += (bytes + 255) & ~(size_t)255;
    return p;
  };
  size_t partial_sz = (size_t)SPLIT * NPAD * 8 * 4;        // 26.2 MB (max of PS=5/8 uses)
  char* region     = carve(partial_sz);
  int* blockBase   = (int*)region;                          // dead after kB
  unsigned* stage  = (unsigned*)(region + (size_t)FILL_BLOCKS * NSB * 4); // dead after kC
  float* partial   = (float*)region;                        // first written by k_aggs<5>
  int* bcnt        = (int*)carve((size_t)NSB * 4);
  int* sboffs      = (int*)carve((size_t)(NSB + 1) * 4);
  int* csr         = (int*)carve((size_t)N_EDGES * 4);
  int* noffs       = (int*)carve((size_t)(N_NODES + 2) * 4);
  int* noffsS      = (int*)carve((size_t)N_NODES * 8 * 4);
  float* dinv      = (float*)carve((size_t)N_NODES * 4);
  float* xd5       = (float*)carve((size_t)NROWS * 5 * 4);  // padded to 49*2048 rows
  float* g2        = (float*)carve((size_t)NROWS * 8 * 4);  // padded to 49*2048 rows
  float* gsum      = (float*)carve((size_t)N_GRAPHS * 8 * 4);

  (void)hipFuncSetAttribute(reinterpret_cast<const void*>(&k_aggs<5>),
                            hipFuncAttributeMaxDynamicSharedMemorySize, 2048 * 5 * 4);
  (void)hipFuncSetAttribute(reinterpret_cast<const void*>(&k_aggs<8>),
                            hipFuncAttributeMaxDynamicSharedMemorySize, 2048 * 9 * 4);

  hipMemsetAsync(bcnt, 0, (size_t)NSB * 4, stream);
  hipMemsetAsync(gsum, 0, (size_t)N_GRAPHS * 8 * 4, stream);

  kA_count<<<FILL_BLOCKS, 256, 0, stream>>>(dstp, bcnt, blockBase);
  k_bscan<<<1, 512, 0, stream>>>(bcnt, sboffs);
  kB_fill<<<FILL_BLOCKS, 256, 0, stream>>>(srcp, dstp, sboffs, blockBase, stage);
  kC_csr<<<NSB, 256, 0, stream>>>(stage, sboffs, x, noffs, noffsS, dinv, xd5, csr);
  k_aggs<5><<<NDB * SPLIT, 512, 2048 * 5 * 4, stream>>>(csr, noffs, noffsS, xd5, partial);
  k_mlp<<<(N_NODES + 255) / 256, 256, 0, stream>>>(partial, xd5, dinv, W1, b1, W2, g2);
  k_aggs<8><<<NDB * SPLIT, 512, 2048 * 9 * 4, stream>>>(csr, noffs, noffsS, g2, partial);
  k_out<<<(N_NODES + 511) / 512, 512, 0, stream>>>(partial, g2, dinv, b2, batch, gsum);
  k_final<<<64, 256, 0, stream>>>(gsum, batch, out);
}

// Round 17
// 318.719 us; speedup vs baseline: 1.1835x; 1.1835x over previous
//
#include <hip/hip_runtime.h>

#define N_NODES 100000
#define N_EDGES 3200000
#define N_GRAPHS 2048
#define SSH 8                       // 256 dst nodes per superbucket
#define SSZ 256
#define NSB 391                     // ceil(100000/256)
#define FILL_BLOCKS 512
#define CHUNK 6250                  // N_EDGES / FILL_BLOCKS
#define NSL 49                      // src slices of 2048 nodes (49*2048 = 100352)
#define NBIN (SSZ * NSL)            // 12544 bins (50KB LDS)
#define DBLK 4096                   // dst nodes per agg block (8/thread, in registers)
#define NDB 25                      // ceil(100000/4096)
#define SPLIT 8
#define NPAD (NDB * DBLK)           // 102400
#define NROWS (NSL * 2048)          // 100352 padded table rows

typedef float f32x4 __attribute__((ext_vector_type(4)));

__device__ __forceinline__ void gAtomAdd(float* p, float v) { unsafeAtomicAdd(p, v); }

// slice -> position so split p's slices (t ≡ p mod 8) are contiguous ascending
__device__ __forceinline__ int slice_pidx(int t) {
  int p = t & 7;
  return (p ? 6 * p + 1 : 0) + (t >> 3);   // split sizes: 7,6,6,6,6,6,6,6
}

// ---------- pass 1: per-block superbucket histogram + reservation (proven) ----------
__global__ void kA_count(const int* __restrict__ dst, int* __restrict__ bcnt,
                         int* __restrict__ blockBase) {
  __shared__ int hist[NSB];
  int tid = threadIdx.x, blk = blockIdx.x;
  for (int i = tid; i < NSB; i += 256) hist[i] = 0;
  __syncthreads();
  int beg = blk * CHUNK, end = beg + CHUNK;
  for (int e = beg + tid; e < end; e += 256) atomicAdd(&hist[dst[e] >> SSH], 1);
  __syncthreads();
  for (int i = tid; i < NSB; i += 256) {
    int h = hist[i];
    if (h) blockBase[blk * NSB + i] = atomicAdd(&bcnt[i], h);
  }
}

// ---------- exclusive scan over NSB counts (proven) ----------
__global__ void k_bscan(const int* __restrict__ bcnt, int* __restrict__ sboffs) {
  __shared__ int sh[512];
  int tid = threadIdx.x;
  int v = (tid < NSB) ? bcnt[tid] : 0;
  sh[tid] = v;
  __syncthreads();
  for (int off = 1; off < 512; off <<= 1) {
    int t = (tid >= off) ? sh[tid - off] : 0;
    __syncthreads();
    sh[tid] += t;
    __syncthreads();
  }
  if (tid < NSB) sboffs[tid] = sh[tid] - v;
  if (tid == 0) sboffs[NSB] = N_EDGES;
}

// ---------- pass 2: scatter packed edges into superbucket segments (proven) ----------
__global__ void kB_fill(const int* __restrict__ src, const int* __restrict__ dst,
                        const int* __restrict__ sboffs, const int* __restrict__ blockBase,
                        unsigned* __restrict__ stage) {
  __shared__ int lbase[NSB];
  int tid = threadIdx.x, blk = blockIdx.x;
  for (int i = tid; i < NSB; i += 256) lbase[i] = sboffs[i] + blockBase[blk * NSB + i];
  __syncthreads();
  int beg = blk * CHUNK, end = beg + CHUNK;
  for (int e = beg + tid; e < end; e += 256) {
    int d = dst[e], s = src[e];
    int pos = atomicAdd(&lbase[d >> SSH], 1);
    stage[pos] = ((unsigned)s << SSH) | (unsigned)(d & (SSZ - 1));  // src:17 | dstloc:8
  }
}

// ---------- pass 3: per-superbucket (node, split-ordered slice) counting sort (proven) ----------
__global__ void kC_csr(const unsigned* __restrict__ stage, const int* __restrict__ sboffs,
                       const float* __restrict__ x, int* __restrict__ noffs,
                       int* __restrict__ noffsS, float* __restrict__ dinv,
                       float* __restrict__ xd5, int* __restrict__ csr) {
  __shared__ int bins[NBIN];                       // 50KB
  __shared__ int sc[SSZ];
  int b = blockIdx.x, tid = threadIdx.x;
  for (int i = tid; i < NBIN; i += 256) bins[i] = 0;
  __syncthreads();
  int beg = sboffs[b], end = sboffs[b + 1];
  for (int k = beg + tid; k < end; k += 256) {
    unsigned u = stage[k];
    int dl = u & (SSZ - 1), s = u >> SSH;
    atomicAdd(&bins[dl * NSL + slice_pidx(s >> 11)], 1);
  }
  __syncthreads();
  int tot = 0;
  for (int j = 0; j < NSL; j++) tot += bins[tid * NSL + j];
  sc[tid] = tot;
  __syncthreads();
  for (int off = 1; off < SSZ; off <<= 1) {
    int t = (tid >= off) ? sc[tid - off] : 0;
    __syncthreads();
    sc[tid] += t;
    __syncthreads();
  }
  int excl = sc[tid] - tot;
  int node = b * SSZ + tid;
  if (node <= N_NODES) noffs[node] = beg + excl;
  if (node < N_NODES) {
    float di = rsqrtf((float)(tot + 1));           // +1 self-loop
    dinv[node] = di;
#pragma unroll
    for (int c = 0; c < 5; c++) xd5[(size_t)node * 5 + c] = x[node * 5 + c] * di;
  }
  int run = beg + excl;
  for (int j = 0; j < NSL; j++) {
    int p = (j == 0) ? 0 : ((j >= 7 && (j - 7) % 6 == 0) ? 1 + (j - 7) / 6 : -1);
    if (p >= 0 && node < N_NODES) noffsS[node * 8 + p] = run;
    int c = bins[tid * NSL + j];
    bins[tid * NSL + j] = run;
    run += c;
  }
  __syncthreads();
  for (int k = beg + tid; k < end; k += 256) {
    unsigned u = stage[k];
    int dl = u & (SSZ - 1), s = u >> SSH;
    int pos = atomicAdd(&bins[dl * NSL + slice_pidx(s >> 11)], 1);
    csr[pos] = s;
  }
}

// ---------- tiled agg: each csr entry read EXACTLY ONCE (snext register carry) ----------
template <int NC>
__global__ void k_aggs(const int* __restrict__ csr, const int* __restrict__ noffs,
                       const int* __restrict__ noffsS, const float* __restrict__ tab,
                       float* __restrict__ partial) {
  constexpr int NCS = (NC == 5) ? 5 : 9;
  constexpr int NREG = (NC == 5) ? 5 : 8;          // float4s staged per thread
  constexpr int PS = (NC == 5) ? 5 : 8;            // partial row stride
  extern __shared__ float slice[];                 // 2048 * NCS floats
  int bx = blockIdx.x;
  int db = bx >> 3, p = bx & 7;
  int base = db * DBLK;
  int tid = threadIdx.x;                           // 512 threads, 8 nodes each
  const float4* tv = (const float4*)tab;

  int kcur[8], kend[8], snext[8];
  float acc[8][NC];
#pragma unroll
  for (int i = 0; i < 8; i++) {
    int n = base + i * 512 + tid;
    if (n < N_NODES) {
      kcur[i] = noffsS[n * 8 + p];
      kend[i] = (p < 7) ? noffsS[n * 8 + p + 1] : noffs[n + 1];
    } else { kcur[i] = 0; kend[i] = 0; }
    snext[i] = (kcur[i] < kend[i]) ? csr[kcur[i]] : 0x7fffffff;   // register carry
#pragma unroll
    for (int c = 0; c < NC; c++) acc[i][c] = 0.f;
  }

  float4 st[NREG];
  int nsl = (NSL - p + 7) / 8;
  {                                                // prologue: issue slice t=p
    size_t fb = (size_t)p * 2048 * NC / 4;
#pragma unroll
    for (int j = 0; j < NREG; j++) st[j] = tv[fb + tid + j * 512];
  }
  for (int si = 0; si < nsl; si++) {
    int t = p + si * 8;
    __syncthreads();                               // prior slice readers done
    if (NC == 5) {
#pragma unroll
      for (int j = 0; j < NREG; j++)               // pure linear copy, b128 LDS writes
        ((float4*)slice)[tid + j * 512] = st[j];
    } else {
#pragma unroll
      for (int j = 0; j < NREG; j++) {             // strided: row r at slice+r*9
        int q = tid + j * 512;
        float* dp = slice + (q >> 1) * 9 + (q & 1) * 4;
        dp[0] = st[j].x; dp[1] = st[j].y; dp[2] = st[j].z; dp[3] = st[j].w;
      }
    }
    __syncthreads();                               // slice visible
    if (si + 1 < nsl) {                            // issue next slice (overlaps processing)
      size_t fb = (size_t)(t + 8) * 2048 * NC / 4;
#pragma unroll
      for (int j = 0; j < NREG; j++) st[j] = tv[fb + tid + j * 512];
    }
#pragma unroll
    for (int i = 0; i < 8; i++) {
      int k = kcur[i], ke = kend[i], s = snext[i];
      while ((s >> 11) == t) {                     // consume carried value; no re-read
        const float* sp = slice + (s & 2047) * NCS;
#pragma unroll
        for (int c = 0; c < NC; c++) acc[i][c] += sp[c];
        k++;
        s = (k < ke) ? csr[k] : 0x7fffffff;        // sequential, read-once
      }
      kcur[i] = k; snext[i] = s;
    }
  }
#pragma unroll
  for (int i = 0; i < 8; i++) {
    int n = base + i * 512 + tid;
    float* pp = partial + ((size_t)p * NPAD + n) * PS;
    if (NC == 8) {                                 // 32B-aligned rows: vector NT stores
      f32x4 v0 = {acc[i][0], acc[i][1], acc[i][2], acc[i][3]};
      f32x4 v1 = {acc[i][4], acc[i][5], acc[i][6], acc[i][7]};
      __builtin_nontemporal_store(v0, (f32x4*)pp);
      __builtin_nontemporal_store(v1, (f32x4*)(pp + 4));
    } else {                                       // 20B rows: scalar NT stores
#pragma unroll
      for (int c = 0; c < NC; c++) __builtin_nontemporal_store(acc[i][c], pp + c);
    }
  }
}

// ---------- layer-1 epilogue: merge partials + self-loop, fused MLP ----------
__global__ void k_mlp(const float* __restrict__ partial, const float* __restrict__ xd5,
                      const float* __restrict__ dinv, const float* __restrict__ W1,
                      const float* __restrict__ b1, const float* __restrict__ W2,
                      float* __restrict__ g2) {
  __shared__ float w1[150], bb1[30], w2[240];
  int tid = threadIdx.x;
  for (int i = tid; i < 150; i += 256) w1[i] = W1[i];
  for (int i = tid; i < 30; i += 256) bb1[i] = b1[i];
  for (int i = tid; i < 240; i += 256) w2[i] = W2[i];
  __syncthreads();
  int n = blockIdx.x * 256 + tid;
  if (n >= N_NODES) return;
  float di = dinv[n];
  float s[5];
#pragma unroll
  for (int c = 0; c < 5; c++) s[c] = xd5[(size_t)n * 5 + c];
#pragma unroll
  for (int p = 0; p < SPLIT; p++) {
    const float* pp = partial + ((size_t)p * NPAD + n) * 5;
#pragma unroll
    for (int c = 0; c < 5; c++) s[c] += pp[c];
  }
  float t[5] = {s[0] * di, s[1] * di, s[2] * di, s[3] * di, s[4] * di};
  float h[30];
#pragma unroll
  for (int j = 0; j < 30; j++) h[j] = bb1[j];
#pragma unroll
  for (int k = 0; k < 5; k++)
#pragma unroll
    for (int j = 0; j < 30; j++) h[j] += t[k] * w1[k * 30 + j];
  float g[8] = {0, 0, 0, 0, 0, 0, 0, 0};
#pragma unroll
  for (int j = 0; j < 30; j++) {
    float hj = fmaxf(h[j], 0.f);
#pragma unroll
    for (int c = 0; c < 8; c++) g[c] += hj * w2[j * 8 + c];
  }
  float4* gv = (float4*)g2;
  gv[n * 2]     = make_float4(g[0] * di, g[1] * di, g[2] * di, g[3] * di);
  gv[n * 2 + 1] = make_float4(g[4] * di, g[5] * di, g[6] * di, g[7] * di);
}

// ---------- layer-2 epilogue: merge partials + bias + pooling (proven) ----------
__global__ void k_out(const float* __restrict__ partial, const float* __restrict__ g2,
                      const float* __restrict__ dinv, const float* __restrict__ b2,
                      const int* __restrict__ batch, float* __restrict__ gsum) {
  __shared__ float gpool[64 * 8];
  __shared__ float bb2[8];
  __shared__ int batch0s;
  int blk = blockIdx.x, tid = threadIdx.x;         // 512 threads
  for (int i = tid; i < 64 * 8; i += 512) gpool[i] = 0.f;
  if (tid < 8) bb2[tid] = b2[tid];
  if (tid == 0) {
    int n0 = blk * 512;
    batch0s = batch[n0 < N_NODES ? n0 : (N_NODES - 1)];
  }
  __syncthreads();
  int n = blk * 512 + tid;
  int batch0 = batch0s;
  if (n < N_NODES) {
    float di = dinv[n];
    int gid = batch[n], goff = gid - batch0;
    float4 s03 = ((const float4*)g2)[n * 2];
    float4 s47 = ((const float4*)g2)[n * 2 + 1];
#pragma unroll
    for (int p = 0; p < SPLIT; p++) {
      const float4* pp = (const float4*)(partial + ((size_t)p * NPAD + n) * 8);
      float4 qa = pp[0], qb = pp[1];
      s03.x += qa.x; s03.y += qa.y; s03.z += qa.z; s03.w += qa.w;
      s47.x += qb.x; s47.y += qb.y; s47.z += qb.z; s47.w += qb.w;
    }
    float val[8] = {di * s03.x + bb2[0], di * s03.y + bb2[1], di * s03.z + bb2[2],
                    di * s03.w + bb2[3], di * s47.x + bb2[4], di * s47.y + bb2[5],
                    di * s47.z + bb2[6], di * s47.w + bb2[7]};
#pragma unroll
    for (int c = 0; c < 8; c++) {
      if (goff < 64) atomicAdd(&gpool[goff * 8 + c], val[c]);
      else           gAtomAdd(&gsum[gid * 8 + c], val[c]);
    }
  }
  __syncthreads();
  for (int i = tid; i < 64 * 8; i += 512) {
    int gid = batch0 + (i >> 3);
    float v = gpool[i];
    if (gid < N_GRAPHS && v != 0.f) gAtomAdd(&gsum[gid * 8 + (i & 7)], v);
  }
}

// ---------- mean divide (proven) ----------
__global__ void k_final(const float* __restrict__ gsum, const int* __restrict__ batch,
                        float* __restrict__ out) {
  int i = blockIdx.x * 256 + threadIdx.x;
  if (i >= N_GRAPHS * 8) return;
  int g = i >> 3;
  int lo = 0, hi = N_NODES;
  while (lo < hi) { int m = (lo + hi) >> 1; if (batch[m] < g) lo = m + 1; else hi = m; }
  int lo2 = lo, hi2 = N_NODES;
  while (lo2 < hi2) { int m = (lo2 + hi2) >> 1; if (batch[m] <= g) lo2 = m + 1; else hi2 = m; }
  float c = (float)(lo2 - lo);
  out[i] = gsum[i] / fmaxf(c, 1.f);
}

extern "C" void kernel_launch(void* const* d_in, const int* in_sizes, int n_in,
                              void* d_out, int out_size, void* d_ws, size_t ws_size,
                              hipStream_t stream) {
  const float* x    = (const float*)d_in[0];
  const int* ei     = (const int*)d_in[1];
  const int* batch  = (const int*)d_in[2];
  const float* W1   = (const float*)d_in[3];
  const float* b1   = (const float*)d_in[4];
  const float* W2   = (const float*)d_in[5];
  const float* b2   = (const float*)d_in[6];
  const int* srcp = ei;
  const int* dstp = ei + N_EDGES;
  float* out = (float*)d_out;

  // workspace carve (~48 MB; partial overlays blockBase+stage which die after kC)
  char* base = (char*)d_ws;
  size_t o = 0;
  auto carve = [&](size_t bytes) -> char* {
    char* p = base + o;
    o += (bytes + 255) & ~(size_t)255;
    return p;
  };
  size_t partial_sz = (size_t)SPLIT * NPAD * 8 * 4;        // 26.2 MB (max of PS=5/8 uses)
  char* region     = carve(partial_sz);
  int* blockBase   = (int*)region;                          // dead after kB
  unsigned* stage  = (unsigned*)(region + (size_t)FILL_BLOCKS * NSB * 4); // dead after kC
  float* partial   = (float*)region;                        // first written by k_aggs<5>
  int* bcnt        = (int*)carve((size_t)NSB * 4);
  int* sboffs      = (int*)carve((size_t)(NSB + 1) * 4);
  int* csr         = (int*)carve((size_t)N_EDGES * 4);
  int* noffs       = (int*)carve((size_t)(N_NODES + 2) * 4);
  int* noffsS      = (int*)carve((size_t)N_NODES * 8 * 4);
  float* dinv      = (float*)carve((size_t)N_NODES * 4);
  float* xd5       = (float*)carve((size_t)NROWS * 5 * 4);  // padded to 49*2048 rows
  float* g2        = (float*)carve((size_t)NROWS * 8 * 4);  // padded to 49*2048 rows
  float* gsum      = (float*)carve((size_t)N_GRAPHS * 8 * 4);

  (void)hipFuncSetAttribute(reinterpret_cast<const void*>(&k_aggs<5>),
                            hipFuncAttributeMaxDynamicSharedMemorySize, 2048 * 5 * 4);
  (void)hipFuncSetAttribute(reinterpret_cast<const void*>(&k_aggs<8>),
                            hipFuncAttributeMaxDynamicSharedMemorySize, 2048 * 9 * 4);

  hipMemsetAsync(bcnt, 0, (size_t)NSB * 4, stream);
  hipMemsetAsync(gsum, 0, (size_t)N_GRAPHS * 8 * 4, stream);

  kA_count<<<FILL_BLOCKS, 256, 0, stream>>>(dstp, bcnt, blockBase);
  k_bscan<<<1, 512, 0, stream>>>(bcnt, sboffs);
  kB_fill<<<FILL_BLOCKS, 256, 0, stream>>>(srcp, dstp, sboffs, blockBase, stage);
  kC_csr<<<NSB, 256, 0, stream>>>(stage, sboffs, x, noffs, noffsS, dinv, xd5, csr);
  k_aggs<5><<<NDB * SPLIT, 512, 2048 * 5 * 4, stream>>>(csr, noffs, noffsS, xd5, partial);
  k_mlp<<<(N_NODES + 255) / 256, 256, 0, stream>>>(partial, xd5, dinv, W1, b1, W2, g2);
  k_aggs<8><<<NDB * SPLIT, 512, 2048 * 9 * 4, stream>>>(csr, noffs, noffsS, g2, partial);
  k_out<<<(N_NODES + 511) / 512, 512, 0, stream>>>(partial, g2, dinv, b2, batch, gsum);
  k_final<<<64, 256, 0, stream>>>(gsum, batch, out);
}

// Round 18
// 191.383 us; speedup vs baseline: 1.9710x; 1.6653x over previous
//
#include <hip/hip_runtime.h>

#define N_NODES 100000
#define N_EDGES 3200000
#define N_GRAPHS 2048
#define SSH 8                       // 256 dst nodes per superbucket
#define SSZ 256
#define NSB 391                     // ceil(100000/256)
#define FILL_BLOCKS 512
#define CHUNK 6250                  // N_EDGES / FILL_BLOCKS
#define CAP 9216                    // fixed slots per superbucket (mean 8184 + 11 sigma)

__device__ __forceinline__ void gAtomAdd(float* p, float v) { unsafeAtomicAdd(p, v); }

// ---------- fused pass: LDS histogram -> global reservation -> scatter ----------
// dst chunk is read twice, but the 2nd read is L2-hot (50KB/block).
__global__ void kAB_fill(const int* __restrict__ src, const int* __restrict__ dst,
                         int* __restrict__ bcnt, unsigned* __restrict__ stage) {
  __shared__ int hist[NSB];
  int tid = threadIdx.x, blk = blockIdx.x;
  for (int i = tid; i < NSB; i += 256) hist[i] = 0;
  __syncthreads();
  int beg = blk * CHUNK, end = beg + CHUNK;
  for (int e = beg + tid; e < end; e += 256) atomicAdd(&hist[dst[e] >> SSH], 1);
  __syncthreads();
  for (int i = tid; i < NSB; i += 256) {
    int h = hist[i];
    if (h) hist[i] = atomicAdd(&bcnt[i], h);      // block's base within superbucket i
  }
  __syncthreads();
  for (int e = beg + tid; e < end; e += 256) {
    int d = dst[e], s = src[e];
    int b = d >> SSH;
    int pos = atomicAdd(&hist[b], 1);             // LDS cursor from reserved base
    stage[(size_t)b * CAP + pos] = ((unsigned)s << SSH) | (unsigned)(d & (SSZ - 1));
  }
}

// ---------- exclusive scan over NSB counts (proven) ----------
__global__ void k_bscan(const int* __restrict__ bcnt, int* __restrict__ sboffs) {
  __shared__ int sh[512];
  int tid = threadIdx.x;
  int v = (tid < NSB) ? bcnt[tid] : 0;
  sh[tid] = v;
  __syncthreads();
  for (int off = 1; off < 512; off <<= 1) {
    int t = (tid >= off) ? sh[tid - off] : 0;
    __syncthreads();
    sh[tid] += t;
    __syncthreads();
  }
  if (tid < NSB) sboffs[tid] = sh[tid] - v;
  if (tid == 0) sboffs[NSB] = N_EDGES;
}

// ---------- per-superbucket node sort -> dense csr + noffs + dinv + xd8 (proven r13) ----------
__global__ void kC_csr(const unsigned* __restrict__ stage, const int* __restrict__ bcnt,
                       const int* __restrict__ sboffs, const float* __restrict__ x,
                       int* __restrict__ noffs, float* __restrict__ dinv,
                       float* __restrict__ xd8, int* __restrict__ csr) {
  __shared__ int cnt[SSZ], sc[SSZ], cur[SSZ];
  int b = blockIdx.x, tid = threadIdx.x;
  cnt[tid] = 0;
  __syncthreads();
  size_t rbeg = (size_t)b * CAP;
  int n_in_b = bcnt[b];
  int wbeg = sboffs[b];
  for (int k = tid; k < n_in_b; k += 256) atomicAdd(&cnt[stage[rbeg + k] & (SSZ - 1)], 1);
  __syncthreads();
  sc[tid] = cnt[tid];
  __syncthreads();
  for (int off = 1; off < SSZ; off <<= 1) {       // inclusive scan over 256
    int t = (tid >= off) ? sc[tid - off] : 0;
    __syncthreads();
    sc[tid] += t;
    __syncthreads();
  }
  int excl = sc[tid] - cnt[tid];
  int node = b * SSZ + tid;
  if (node <= N_NODES) noffs[node] = wbeg + excl;  // dense exclusive offsets
  if (node < N_NODES) {
    float di = rsqrtf((float)(cnt[tid] + 1));      // +1 self-loop
    dinv[node] = di;
    float r[5];
#pragma unroll
    for (int c = 0; c < 5; c++) r[c] = x[node * 5 + c] * di;
    float4* xv = (float4*)xd8;
    xv[node * 2]     = make_float4(r[0], r[1], r[2], r[3]);
    xv[node * 2 + 1] = make_float4(r[4], 0.f, 0.f, 0.f);
  }
  cur[tid] = wbeg + excl;
  __syncthreads();
  for (int k = tid; k < n_in_b; k += 256) {
    unsigned u = stage[rbeg + k];
    int pos = atomicAdd(&cur[u & (SSZ - 1)], 1);
    csr[pos] = (int)(u >> SSH);
  }
}

// ---------- layer-1: per-node register accumulation + fused MLP (proven r12/r13) ----------
__global__ void k_agg1(const int* __restrict__ csr, const int* __restrict__ noffs,
                       const float* __restrict__ xd8, const float* __restrict__ dinv,
                       const float* __restrict__ W1, const float* __restrict__ b1,
                       const float* __restrict__ W2, float* __restrict__ g2) {
  __shared__ float w1[150], bb1[30], w2[240];
  int tid = threadIdx.x;
  for (int i = tid; i < 150; i += 256) w1[i] = W1[i];
  for (int i = tid; i < 30; i += 256) bb1[i] = b1[i];
  for (int i = tid; i < 240; i += 256) w2[i] = W2[i];
  __syncthreads();
  int n = blockIdx.x * 256 + tid;
  if (n >= N_NODES) return;
  const float4* xv = (const float4*)xd8;
  float a0 = 0, a1 = 0, a2 = 0, a3 = 0, a4 = 0;
  int k = noffs[n], end = noffs[n + 1];
  for (; k + 4 <= end; k += 4) {
    int s0 = csr[k], s1 = csr[k + 1], s2 = csr[k + 2], s3 = csr[k + 3];
    float4 q0 = xv[s0 * 2], q1 = xv[s1 * 2], q2 = xv[s2 * 2], q3 = xv[s3 * 2];
    float c0 = xd8[s0 * 8 + 4], c1 = xd8[s1 * 8 + 4], c2 = xd8[s2 * 8 + 4], c3 = xd8[s3 * 8 + 4];
    a0 += q0.x + q1.x + q2.x + q3.x;
    a1 += q0.y + q1.y + q2.y + q3.y;
    a2 += q0.z + q1.z + q2.z + q3.z;
    a3 += q0.w + q1.w + q2.w + q3.w;
    a4 += c0 + c1 + c2 + c3;
  }
  for (; k < end; k++) {
    int s = csr[k];
    float4 q = xv[s * 2];
    a0 += q.x; a1 += q.y; a2 += q.z; a3 += q.w; a4 += xd8[s * 8 + 4];
  }
  float di = dinv[n];
  float t[5] = {(a0 + xd8[n * 8 + 0]) * di, (a1 + xd8[n * 8 + 1]) * di,
                (a2 + xd8[n * 8 + 2]) * di, (a3 + xd8[n * 8 + 3]) * di,
                (a4 + xd8[n * 8 + 4]) * di};
  float h[30];
#pragma unroll
  for (int j = 0; j < 30; j++) h[j] = bb1[j];
#pragma unroll
  for (int kk = 0; kk < 5; kk++)
#pragma unroll
    for (int j = 0; j < 30; j++) h[j] += t[kk] * w1[kk * 30 + j];
  float g[8] = {0, 0, 0, 0, 0, 0, 0, 0};
#pragma unroll
  for (int j = 0; j < 30; j++) {
    float hj = fmaxf(h[j], 0.f);
#pragma unroll
    for (int c = 0; c < 8; c++) g[c] += hj * w2[j * 8 + c];
  }
  float4* gv = (float4*)g2;
  gv[n * 2]     = make_float4(g[0] * di, g[1] * di, g[2] * di, g[3] * di);
  gv[n * 2 + 1] = make_float4(g[4] * di, g[5] * di, g[6] * di, g[7] * di);
}

// ---------- layer-2: per-node register accumulation + fused pooling (proven r12/r13) ----------
__global__ void k_agg2(const int* __restrict__ csr, const int* __restrict__ noffs,
                       const float* __restrict__ g2, const float* __restrict__ dinv,
                       const float* __restrict__ b2, const int* __restrict__ batch,
                       float* __restrict__ gsum) {
  __shared__ float gpool[64 * 8];
  __shared__ float bb2[8];
  __shared__ int batch0s;
  int blk = blockIdx.x, tid = threadIdx.x;
  for (int i = tid; i < 64 * 8; i += 256) gpool[i] = 0.f;
  if (tid < 8) bb2[tid] = b2[tid];
  if (tid == 0) {
    int n0 = blk * 256;
    batch0s = batch[n0 < N_NODES ? n0 : (N_NODES - 1)];
  }
  __syncthreads();
  int n = blk * 256 + tid;
  int batch0 = batch0s;
  if (n < N_NODES) {
    const float4* gv = (const float4*)g2;
    float4 lo = make_float4(0, 0, 0, 0), hi = make_float4(0, 0, 0, 0);
    int k = noffs[n], end = noffs[n + 1];
    for (; k + 2 <= end; k += 2) {
      int s0 = csr[k], s1 = csr[k + 1];
      float4 p0 = gv[s0 * 2], q0 = gv[s0 * 2 + 1];
      float4 p1 = gv[s1 * 2], q1 = gv[s1 * 2 + 1];
      lo.x += p0.x + p1.x; lo.y += p0.y + p1.y;
      lo.z += p0.z + p1.z; lo.w += p0.w + p1.w;
      hi.x += q0.x + q1.x; hi.y += q0.y + q1.y;
      hi.z += q0.z + q1.z; hi.w += q0.w + q1.w;
    }
    for (; k < end; k++) {
      int s = csr[k];
      float4 p = gv[s * 2], q = gv[s * 2 + 1];
      lo.x += p.x; lo.y += p.y; lo.z += p.z; lo.w += p.w;
      hi.x += q.x; hi.y += q.y; hi.z += q.z; hi.w += q.w;
    }
    float di = dinv[n];
    float4 sl = gv[n * 2], sh = gv[n * 2 + 1];    // self-loop
    float val[8] = {di * (lo.x + sl.x) + bb2[0], di * (lo.y + sl.y) + bb2[1],
                    di * (lo.z + sl.z) + bb2[2], di * (lo.w + sl.w) + bb2[3],
                    di * (hi.x + sh.x) + bb2[4], di * (hi.y + sh.y) + bb2[5],
                    di * (hi.z + sh.z) + bb2[6], di * (hi.w + sh.w) + bb2[7]};
    int gid = batch[n], goff = gid - batch0;
#pragma unroll
    for (int c = 0; c < 8; c++) {
      if (goff < 64) atomicAdd(&gpool[goff * 8 + c], val[c]);
      else           gAtomAdd(&gsum[gid * 8 + c], val[c]);
    }
  }
  __syncthreads();
  for (int i = tid; i < 64 * 8; i += 256) {
    int gid = batch0 + (i >> 3);
    float v = gpool[i];
    if (gid < N_GRAPHS && v != 0.f) gAtomAdd(&gsum[gid * 8 + (i & 7)], v);
  }
}

// ---------- mean divide (proven) ----------
__global__ void k_final(const float* __restrict__ gsum, const int* __restrict__ batch,
                        float* __restrict__ out) {
  int i = blockIdx.x * 256 + threadIdx.x;
  if (i >= N_GRAPHS * 8) return;
  int g = i >> 3;
  int lo = 0, hi = N_NODES;
  while (lo < hi) { int m = (lo + hi) >> 1; if (batch[m] < g) lo = m + 1; else hi = m; }
  int lo2 = lo, hi2 = N_NODES;
  while (lo2 < hi2) { int m = (lo2 + hi2) >> 1; if (batch[m] <= g) lo2 = m + 1; else hi2 = m; }
  float c = (float)(lo2 - lo);
  out[i] = gsum[i] / fmaxf(c, 1.f);
}

extern "C" void kernel_launch(void* const* d_in, const int* in_sizes, int n_in,
                              void* d_out, int out_size, void* d_ws, size_t ws_size,
                              hipStream_t stream) {
  const float* x    = (const float*)d_in[0];
  const int* ei     = (const int*)d_in[1];
  const int* batch  = (const int*)d_in[2];
  const float* W1   = (const float*)d_in[3];
  const float* b1   = (const float*)d_in[4];
  const float* W2   = (const float*)d_in[5];
  const float* b2   = (const float*)d_in[6];
  const int* srcp = ei;
  const int* dstp = ei + N_EDGES;
  float* out = (float*)d_out;

  // workspace carve (~35 MB)
  char* base = (char*)d_ws;
  size_t o = 0;
  auto carve = [&](size_t bytes) -> char* {
    char* p = base + o;
    o += (bytes + 255) & ~(size_t)255;
    return p;
  };
  int* bcnt        = (int*)carve((size_t)NSB * 4);
  int* sboffs      = (int*)carve((size_t)(NSB + 1) * 4);
  unsigned* stage  = (unsigned*)carve((size_t)NSB * CAP * 4);   // 14.4 MB, fixed-cap
  int* csr         = (int*)carve((size_t)N_EDGES * 4);
  int* noffs       = (int*)carve((size_t)(N_NODES + 2) * 4);
  float* dinv      = (float*)carve((size_t)N_NODES * 4);
  float* xd8       = (float*)carve((size_t)N_NODES * 8 * 4);
  float* g2        = (float*)carve((size_t)N_NODES * 8 * 4);
  float* gsum      = (float*)carve((size_t)N_GRAPHS * 8 * 4);

  hipMemsetAsync(bcnt, 0, (size_t)NSB * 4, stream);
  hipMemsetAsync(gsum, 0, (size_t)N_GRAPHS * 8 * 4, stream);

  kAB_fill<<<FILL_BLOCKS, 256, 0, stream>>>(srcp, dstp, bcnt, stage);
  k_bscan<<<1, 512, 0, stream>>>(bcnt, sboffs);
  kC_csr<<<NSB, 256, 0, stream>>>(stage, bcnt, sboffs, x, noffs, dinv, xd8, csr);
  k_agg1<<<(N_NODES + 255) / 256, 256, 0, stream>>>(csr, noffs, xd8, dinv, W1, b1, W2, g2);
  k_agg2<<<(N_NODES + 255) / 256, 256, 0, stream>>>(csr, noffs, g2, dinv, b2, batch, gsum);
  k_final<<<64, 256, 0, stream>>>(gsum, batch, out);
}

// Round 19
// 184.675 us; speedup vs baseline: 2.0426x; 1.0363x over previous
//
#include <hip/hip_runtime.h>

#define N_NODES 100000
#define N_EDGES 3200000
#define N_GRAPHS 2048
#define SSH 8                       // 256 dst nodes per superbucket
#define SSZ 256
#define NSB 391                     // ceil(100000/256)
#define CAP 12800                   // slots per superbucket region (mult of 16)
#define WC_BLOCKS 256
#define WC_THREADS 1024
#define WC_EPB 12500                // N_EDGES / WC_BLOCKS
#define WC_SUB 4096
#define CAPB 56                     // per-bin LDS write-combine buffer entries
#define SENT 0xFFFFFFFFu

__device__ __forceinline__ void gAtomAdd(float* p, float v) { unsafeAtomicAdd(p, v); }

// ---------- fused fill with software write-combining ----------
// phase 1: LDS histogram -> 16-aligned global reservation.
// then 4 sub-chunks: {append to per-bin LDS buffers} barrier {flush 64B groups}.
// final: sentinel-pad remainder to a full group. All stage stores are 64B-aligned lines.
__global__ void kAB_wc(const int* __restrict__ src, const int* __restrict__ dst,
                       int* __restrict__ bpad, int* __restrict__ rcnt,
                       unsigned* __restrict__ stage) {
  __shared__ int lbase[NSB], ctr[NSB];
  extern __shared__ unsigned buf[];              // [NSB][CAPB], 87.6 KB dynamic
  int tid = threadIdx.x, blk = blockIdx.x;
  int beg = blk * WC_EPB, end = beg + WC_EPB;
  for (int i = tid; i < NSB; i += WC_THREADS) ctr[i] = 0;
  __syncthreads();
  for (int e = beg + tid; e < end; e += WC_THREADS)       // phase 1: histogram
    atomicAdd(&ctr[dst[e] >> SSH], 1);
  __syncthreads();
  for (int i = tid; i < NSB; i += WC_THREADS) {           // padded reservation
    int h = ctr[i];
    int hp = (h + 15) & ~15;
    int base = 0;
    if (hp) base = atomicAdd(&bpad[i], hp);
    if (h) atomicAdd(&rcnt[i], h);
    lbase[i] = i * CAP + base;                  // 16-aligned (CAP%16==0, hp%16==0)
    ctr[i] = 0;
  }
  __syncthreads();
  for (int sc = 0; sc < WC_EPB; sc += WC_SUB) {
    int send = beg + sc + WC_SUB; if (send > end) send = end;
    for (int e = beg + sc + tid; e < send; e += WC_THREADS) {   // append
      int d = dst[e], s = src[e];
      int b = d >> SSH;
      int pos = atomicAdd(&ctr[b], 1);
      buf[b * CAPB + pos] = ((unsigned)s << SSH) | (unsigned)(d & (SSZ - 1));
    }
    __syncthreads();
    for (int b = tid; b < NSB; b += WC_THREADS) {               // flush full groups
      int c = ctr[b];
      int g = c >> 4;
      if (g) {
        unsigned* bb = &buf[b * CAPB];
        int gb = lbase[b];
        for (int q = 0; q < g; q++) {
          uint4* dp = (uint4*)&stage[gb + q * 16];
          const uint4* sp = (const uint4*)&bb[q * 16];
          dp[0] = sp[0]; dp[1] = sp[1]; dp[2] = sp[2]; dp[3] = sp[3];  // one 64B line
        }
        lbase[b] = gb + g * 16;
        int rem = c & 15;
        for (int j = 0; j < rem; j++) bb[j] = bb[g * 16 + j];
        ctr[b] = rem;
      }
    }
    __syncthreads();
  }
  for (int b = tid; b < NSB; b += WC_THREADS) {                 // final sentinel-padded flush
    int c = ctr[b];
    if (c) {
      unsigned* bb = &buf[b * CAPB];
      for (int j = c; j < 16; j++) bb[j] = SENT;
      uint4* dp = (uint4*)&stage[lbase[b]];
      const uint4* sp = (const uint4*)bb;
      dp[0] = sp[0]; dp[1] = sp[1]; dp[2] = sp[2]; dp[3] = sp[3];
    }
  }
}

// ---------- exclusive scan over NSB REAL counts (proven) ----------
__global__ void k_bscan(const int* __restrict__ rcnt, int* __restrict__ sboffs) {
  __shared__ int sh[512];
  int tid = threadIdx.x;
  int v = (tid < NSB) ? rcnt[tid] : 0;
  sh[tid] = v;
  __syncthreads();
  for (int off = 1; off < 512; off <<= 1) {
    int t = (tid >= off) ? sh[tid - off] : 0;
    __syncthreads();
    sh[tid] += t;
    __syncthreads();
  }
  if (tid < NSB) sboffs[tid] = sh[tid] - v;
  if (tid == 0) sboffs[NSB] = N_EDGES;
}

// ---------- per-superbucket node sort -> dense csr + noffs + dinv + xd8 (proven, +sentinel skip) ----------
__global__ void kC_csr(const unsigned* __restrict__ stage, const int* __restrict__ bpad,
                       const int* __restrict__ sboffs, const float* __restrict__ x,
                       int* __restrict__ noffs, float* __restrict__ dinv,
                       float* __restrict__ xd8, int* __restrict__ csr) {
  __shared__ int cnt[SSZ], sc[SSZ], cur[SSZ];
  int b = blockIdx.x, tid = threadIdx.x;
  cnt[tid] = 0;
  __syncthreads();
  size_t rbeg = (size_t)b * CAP;
  int pcnt = bpad[b];                            // padded slot count
  int wbeg = sboffs[b];
  for (int k = tid; k < pcnt; k += 256) {
    unsigned u = stage[rbeg + k];
    if (u != SENT) atomicAdd(&cnt[u & (SSZ - 1)], 1);
  }
  __syncthreads();
  sc[tid] = cnt[tid];
  __syncthreads();
  for (int off = 1; off < SSZ; off <<= 1) {      // inclusive scan over 256
    int t = (tid >= off) ? sc[tid - off] : 0;
    __syncthreads();
    sc[tid] += t;
    __syncthreads();
  }
  int excl = sc[tid] - cnt[tid];
  int node = b * SSZ + tid;
  if (node <= N_NODES) noffs[node] = wbeg + excl;
  if (node < N_NODES) {
    float di = rsqrtf((float)(cnt[tid] + 1));    // +1 self-loop
    dinv[node] = di;
    float r[5];
#pragma unroll
    for (int c = 0; c < 5; c++) r[c] = x[node * 5 + c] * di;
    float4* xv = (float4*)xd8;
    xv[node * 2]     = make_float4(r[0], r[1], r[2], r[3]);
    xv[node * 2 + 1] = make_float4(r[4], 0.f, 0.f, 0.f);
  }
  cur[tid] = wbeg + excl;
  __syncthreads();
  for (int k = tid; k < pcnt; k += 256) {
    unsigned u = stage[rbeg + k];
    if (u != SENT) {
      int pos = atomicAdd(&cur[u & (SSZ - 1)], 1);
      csr[pos] = (int)(u >> SSH);
    }
  }
}

// ---------- layer-1: per-node register accumulation + fused MLP (proven) ----------
__global__ void k_agg1(const int* __restrict__ csr, const int* __restrict__ noffs,
                       const float* __restrict__ xd8, const float* __restrict__ dinv,
                       const float* __restrict__ W1, const float* __restrict__ b1,
                       const float* __restrict__ W2, float* __restrict__ g2) {
  __shared__ float w1[150], bb1[30], w2[240];
  int tid = threadIdx.x;
  for (int i = tid; i < 150; i += 256) w1[i] = W1[i];
  for (int i = tid; i < 30; i += 256) bb1[i] = b1[i];
  for (int i = tid; i < 240; i += 256) w2[i] = W2[i];
  __syncthreads();
  int n = blockIdx.x * 256 + tid;
  if (n >= N_NODES) return;
  const float4* xv = (const float4*)xd8;
  float a0 = 0, a1 = 0, a2 = 0, a3 = 0, a4 = 0;
  int k = noffs[n], end = noffs[n + 1];
  for (; k + 4 <= end; k += 4) {
    int s0 = csr[k], s1 = csr[k + 1], s2 = csr[k + 2], s3 = csr[k + 3];
    float4 q0 = xv[s0 * 2], q1 = xv[s1 * 2], q2 = xv[s2 * 2], q3 = xv[s3 * 2];
    float c0 = xd8[s0 * 8 + 4], c1 = xd8[s1 * 8 + 4], c2 = xd8[s2 * 8 + 4], c3 = xd8[s3 * 8 + 4];
    a0 += q0.x + q1.x + q2.x + q3.x;
    a1 += q0.y + q1.y + q2.y + q3.y;
    a2 += q0.z + q1.z + q2.z + q3.z;
    a3 += q0.w + q1.w + q2.w + q3.w;
    a4 += c0 + c1 + c2 + c3;
  }
  for (; k < end; k++) {
    int s = csr[k];
    float4 q = xv[s * 2];
    a0 += q.x; a1 += q.y; a2 += q.z; a3 += q.w; a4 += xd8[s * 8 + 4];
  }
  float di = dinv[n];
  float t[5] = {(a0 + xd8[n * 8 + 0]) * di, (a1 + xd8[n * 8 + 1]) * di,
                (a2 + xd8[n * 8 + 2]) * di, (a3 + xd8[n * 8 + 3]) * di,
                (a4 + xd8[n * 8 + 4]) * di};
  float h[30];
#pragma unroll
  for (int j = 0; j < 30; j++) h[j] = bb1[j];
#pragma unroll
  for (int kk = 0; kk < 5; kk++)
#pragma unroll
    for (int j = 0; j < 30; j++) h[j] += t[kk] * w1[kk * 30 + j];
  float g[8] = {0, 0, 0, 0, 0, 0, 0, 0};
#pragma unroll
  for (int j = 0; j < 30; j++) {
    float hj = fmaxf(h[j], 0.f);
#pragma unroll
    for (int c = 0; c < 8; c++) g[c] += hj * w2[j * 8 + c];
  }
  float4* gv = (float4*)g2;
  gv[n * 2]     = make_float4(g[0] * di, g[1] * di, g[2] * di, g[3] * di);
  gv[n * 2 + 1] = make_float4(g[4] * di, g[5] * di, g[6] * di, g[7] * di);
}

// ---------- layer-2: per-node register accumulation + fused pooling (proven) ----------
__global__ void k_agg2(const int* __restrict__ csr, const int* __restrict__ noffs,
                       const float* __restrict__ g2, const float* __restrict__ dinv,
                       const float* __restrict__ b2, const int* __restrict__ batch,
                       float* __restrict__ gsum) {
  __shared__ float gpool[64 * 8];
  __shared__ float bb2[8];
  __shared__ int batch0s;
  int blk = blockIdx.x, tid = threadIdx.x;
  for (int i = tid; i < 64 * 8; i += 256) gpool[i] = 0.f;
  if (tid < 8) bb2[tid] = b2[tid];
  if (tid == 0) {
    int n0 = blk * 256;
    batch0s = batch[n0 < N_NODES ? n0 : (N_NODES - 1)];
  }
  __syncthreads();
  int n = blk * 256 + tid;
  int batch0 = batch0s;
  if (n < N_NODES) {
    const float4* gv = (const float4*)g2;
    float4 lo = make_float4(0, 0, 0, 0), hi = make_float4(0, 0, 0, 0);
    int k = noffs[n], end = noffs[n + 1];
    for (; k + 2 <= end; k += 2) {
      int s0 = csr[k], s1 = csr[k + 1];
      float4 p0 = gv[s0 * 2], q0 = gv[s0 * 2 + 1];
      float4 p1 = gv[s1 * 2], q1 = gv[s1 * 2 + 1];
      lo.x += p0.x + p1.x; lo.y += p0.y + p1.y;
      lo.z += p0.z + p1.z; lo.w += p0.w + p1.w;
      hi.x += q0.x + q1.x; hi.y += q0.y + q1.y;
      hi.z += q0.z + q1.z; hi.w += q0.w + q1.w;
    }
    for (; k < end; k++) {
      int s = csr[k];
      float4 p = gv[s * 2], q = gv[s * 2 + 1];
      lo.x += p.x; lo.y += p.y; lo.z += p.z; lo.w += p.w;
      hi.x += q.x; hi.y += q.y; hi.z += q.z; hi.w += q.w;
    }
    float di = dinv[n];
    float4 sl = gv[n * 2], sh = gv[n * 2 + 1];   // self-loop
    float val[8] = {di * (lo.x + sl.x) + bb2[0], di * (lo.y + sl.y) + bb2[1],
                    di * (lo.z + sl.z) + bb2[2], di * (lo.w + sl.w) + bb2[3],
                    di * (hi.x + sh.x) + bb2[4], di * (hi.y + sh.y) + bb2[5],
                    di * (hi.z + sh.z) + bb2[6], di * (hi.w + sh.w) + bb2[7]};
    int gid = batch[n], goff = gid - batch0;
#pragma unroll
    for (int c = 0; c < 8; c++) {
      if (goff < 64) atomicAdd(&gpool[goff * 8 + c], val[c]);
      else           gAtomAdd(&gsum[gid * 8 + c], val[c]);
    }
  }
  __syncthreads();
  for (int i = tid; i < 64 * 8; i += 256) {
    int gid = batch0 + (i >> 3);
    float v = gpool[i];
    if (gid < N_GRAPHS && v != 0.f) gAtomAdd(&gsum[gid * 8 + (i & 7)], v);
  }
}

// ---------- mean divide (proven) ----------
__global__ void k_final(const float* __restrict__ gsum, const int* __restrict__ batch,
                        float* __restrict__ out) {
  int i = blockIdx.x * 256 + threadIdx.x;
  if (i >= N_GRAPHS * 8) return;
  int g = i >> 3;
  int lo = 0, hi = N_NODES;
  while (lo < hi) { int m = (lo + hi) >> 1; if (batch[m] < g) lo = m + 1; else hi = m; }
  int lo2 = lo, hi2 = N_NODES;
  while (lo2 < hi2) { int m = (lo2 + hi2) >> 1; if (batch[m] <= g) lo2 = m + 1; else hi2 = m; }
  float c = (float)(lo2 - lo);
  out[i] = gsum[i] / fmaxf(c, 1.f);
}

extern "C" void kernel_launch(void* const* d_in, const int* in_sizes, int n_in,
                              void* d_out, int out_size, void* d_ws, size_t ws_size,
                              hipStream_t stream) {
  const float* x    = (const float*)d_in[0];
  const int* ei     = (const int*)d_in[1];
  const int* batch  = (const int*)d_in[2];
  const float* W1   = (const float*)d_in[3];
  const float* b1   = (const float*)d_in[4];
  const float* W2   = (const float*)d_in[5];
  const float* b2   = (const float*)d_in[6];
  const int* srcp = ei;
  const int* dstp = ei + N_EDGES;
  float* out = (float*)d_out;

  // workspace carve (~41 MB)
  char* base = (char*)d_ws;
  size_t o = 0;
  auto carve = [&](size_t bytes) -> char* {
    char* p = base + o;
    o += (bytes + 255) & ~(size_t)255;
    return p;
  };
  int* bpad        = (int*)carve((size_t)NSB * 4);
  int* rcnt        = (int*)carve((size_t)NSB * 4);
  int* sboffs      = (int*)carve((size_t)(NSB + 1) * 4);
  unsigned* stage  = (unsigned*)carve((size_t)NSB * CAP * 4);   // 20 MB, 16-aligned regions
  int* csr         = (int*)carve((size_t)N_EDGES * 4);
  int* noffs       = (int*)carve((size_t)(N_NODES + 2) * 4);
  float* dinv      = (float*)carve((size_t)N_NODES * 4);
  float* xd8       = (float*)carve((size_t)N_NODES * 8 * 4);
  float* g2        = (float*)carve((size_t)N_NODES * 8 * 4);
  float* gsum      = (float*)carve((size_t)N_GRAPHS * 8 * 4);

  (void)hipFuncSetAttribute(reinterpret_cast<const void*>(&kAB_wc),
                            hipFuncAttributeMaxDynamicSharedMemorySize,
                            NSB * CAPB * 4);

  hipMemsetAsync(bpad, 0, (size_t)NSB * 4, stream);
  hipMemsetAsync(rcnt, 0, (size_t)NSB * 4, stream);
  hipMemsetAsync(gsum, 0, (size_t)N_GRAPHS * 8 * 4, stream);

  kAB_wc<<<WC_BLOCKS, WC_THREADS, NSB * CAPB * 4, stream>>>(srcp, dstp, bpad, rcnt, stage);
  k_bscan<<<1, 512, 0, stream>>>(rcnt, sboffs);
  kC_csr<<<NSB, 256, 0, stream>>>(stage, bpad, sboffs, x, noffs, dinv, xd8, csr);
  k_agg1<<<(N_NODES + 255) / 256, 256, 0, stream>>>(csr, noffs, xd8, dinv, W1, b1, W2, g2);
  k_agg2<<<(N_NODES + 255) / 256, 256, 0, stream>>>(csr, noffs, g2, dinv, b2, batch, gsum);
  k_final<<<64, 256, 0, stream>>>(gsum, batch, out);
}